// Round 8
// baseline (18000.237 us; speedup 1.0000x reference)
//
#include <hip/hip_runtime.h>
#include <stdint.h>

// 2-layer LSTM (B=512,T=1024,I=80,H=160) on MI355X gfx950.
// Round-10: FUSED BATCH-PAIR BLOCKS (2x TLP). Evidence: R7 showed stall=49%
// of active-SIMD time with only 2 waves/SIMD; cutting VALU (R7) grew stall
// 1:1 -> latency-bound, needs TLP. This round: 1024-thread blocks, 16 waves
// = 2 symmetric batch-halves (groups 2bi, 2bi+1) running the same stage.
// Weights in LDS shared between halves (80KB once); per-half h/x buffers.
// Each SIMD: 4 waves -> stall slots filled by the other half's waves.
// Per-wave code identical to verified R7 (exp2 weight-fold, builtins-only,
// software-RNE f2bf, tag=t+1 ring, full-ring memset). Pure re-indexing:
// w8=w&7, half=w>>3, gid=2*bi+half. 32 blocks (16 A + 16 B).
// 1024-thr block forces <=128 VGPR: R7 compiled at exactly 128.

#define TT 1024
#define BATCH 512
#define II 80
#define HH 160

constexpr int BB    = 16;
constexpr int NGRP  = BATCH / BB;   // 32
constexpr int NW    = 8;            // waves per half
constexpr int NTHR  = 1024;         // 16 waves
constexpr int NTILE = 5;            // 40 col-tiles / 8 waves
constexpr int DEPTH = 32;           // h-ring depth (power of 2)
constexpr int HP    = 168;          // LDS h row stride (shorts)
constexpr int XP    = 88;           // LDS x row stride (shorts)

typedef __attribute__((ext_vector_type(8))) short s8b;
typedef __attribute__((ext_vector_type(4))) short s4b;
typedef __attribute__((ext_vector_type(4))) float f4;

// ring: per slot, 3 words x 320 lanes (u64) = 960 u64 = 7680 B, word-major
constexpr int SLOT_U64 = 960;
constexpr size_t OFF_RING = 4096;
constexpr size_t RING_STRIDE = (size_t)DEPTH * SLOT_U64 * 8;   // 245760 B/group
constexpr size_t WS_ZERO = OFF_RING + (size_t)NGRP * RING_STRIDE; // 7868416

// dynamic LDS layout (bytes). Weights [0,81920) shared by both halves.
// A: hsh(half)=81920+half*10752; xsh(half)=103424+half*5632   (ends 114688)
// B: h0l(half)=81920+half*10752; hsh(half)=103424+half*10752;
//    ypart(half)=124928+half*1024; bias4=126976 (2560)        (ends 129536)
constexpr int SMEM_SZ = 131072;

constexpr float KLOG2E  = 1.4426950408889634f;
constexpr float KLOG2E2 = 2.8853900817779268f;

__device__ __forceinline__ short f2bf(float x){
  uint32_t u = __builtin_bit_cast(uint32_t, x);
  u = (u + 0x7FFFu + ((u >> 16) & 1u)) >> 16;     // RNE (proven)
  return (short)u;
}
__device__ __forceinline__ float rcpf(float x){ return __builtin_amdgcn_rcpf(x); }
__device__ __forceinline__ float exp2f_(float x){ return __builtin_amdgcn_exp2f(x); }
// pre-activation a already scaled by log2(e) (folded into W,b)
__device__ __forceinline__ float sig2(float a){ return rcpf(1.f + exp2f_(-a)); }
// a scaled by 2*log2(e)
__device__ __forceinline__ float tanh2(float a){ return 1.f - 2.f*rcpf(exp2f_(a) + 1.f); }

__device__ __forceinline__ f4 mfma16(s8b a, s8b b, f4 c){
  return __builtin_amdgcn_mfma_f32_16x16x32_bf16(a, b, c, 0, 0, 0);
}

__device__ __forceinline__ float4 ld4(const float* p){ return *(const float4*)p; }
__device__ __forceinline__ s8b wfrag_s(const float* p, float sc){
  float4 a = ld4(p), b = ld4(p+4);
  s8b r;
  r[0]=f2bf(a.x*sc); r[1]=f2bf(a.y*sc); r[2]=f2bf(a.z*sc); r[3]=f2bf(a.w*sc);
  r[4]=f2bf(b.x*sc); r[5]=f2bf(b.y*sc); r[6]=f2bf(b.z*sc); r[7]=f2bf(b.w*sc);
  return r;
}

__device__ __forceinline__ void st64(unsigned long long* p, unsigned long long v){
  __hip_atomic_store(p, v, __ATOMIC_RELAXED, __HIP_MEMORY_SCOPE_AGENT);
}
__device__ __forceinline__ unsigned long long ld64(const unsigned long long* p){
  return __hip_atomic_load(p, __ATOMIC_RELAXED, __HIP_MEMORY_SCOPE_AGENT);
}
__device__ __forceinline__ void poll_ge(int* p, int& shadow, int target, int lane){
  while (shadow < target){
    int v = 0;
    if (lane == 0) v = __hip_atomic_load(p, __ATOMIC_ACQUIRE, __HIP_MEMORY_SCOPE_AGENT);
    shadow = __shfl(v, 0, 64);
    if (shadow < target) __builtin_amdgcn_s_sleep(2);
  }
}

__global__ __launch_bounds__(NTHR, 1)   // 1024 thr: 4 waves/SIMD -> 128-reg cap
void lstm2(const float* __restrict__ x,
           const float* __restrict__ Wih0, const float* __restrict__ Whh0,
           const float* __restrict__ bih0, const float* __restrict__ bhh0,
           const float* __restrict__ Wih1, const float* __restrict__ Whh1,
           const float* __restrict__ bih1, const float* __restrict__ bhh1,
           const float* __restrict__ Wout, const float* __restrict__ bout,
           float* __restrict__ out, char* __restrict__ ws)
{
  extern __shared__ char smem[];
  const int tid  = threadIdx.x;
  const int w    = tid >> 6;        // 0..15
  const int half = w >> 3;          // batch-half within block
  const int w8   = w & 7;           // wave index within half
  const int l    = tid & 63;
  const int lq   = l >> 4;
  const int lr   = l & 15;
  const int q    = l & 3;           // weight-row gate index
  const int h2   = (l >> 2) & 3;    // weight-row unit-sub index
  const int stage = blockIdx.x >> 4;        // 0=A (blocks 0..15), 1=B (16..31)
  const int bi    = blockIdx.x & 15;
  const int gid   = bi*2 + half;            // group handled by this half
  const int b0    = gid * BB;
  const int li    = w8*64 + l;              // ring lane index (word-major)
  const float wsc = (q == 2) ? KLOG2E2 : KLOG2E;   // fold scale

  int* prog = (int*)ws + gid;   // consumer progress (credit to A), per group
  unsigned long long* ring =
      (unsigned long long*)(ws + OFF_RING + (size_t)gid * RING_STRIDE);

  const s8b zf = {};

  if (stage == 0){
    // ================= stage A: layer 0 (two halves) =================
    // Whh0 (25 frags) + Wih0 kt2 (5) in regs; Wih0 kt0,1 (10) in LDS (shared).
    short* hsh = (short*)(smem + 81920 + half*10752);   // [2][16*HP]
    short* xsh = (short*)(smem + 103424 + half*5632);   // [2][16*XP]
    s8b Wh[NTILE][5], Wi2[NTILE];
    f4 biasv[NTILE];
    #pragma unroll
    for (int s = 0; s < NTILE; ++s){
      const int ct = w8 + 8*s;
      const int wrow = q*HH + 4*ct + h2;
      const int u = 4*ct + lq;                          // per-lane unit
      #pragma unroll
      for (int g = 0; g < 4; ++g)
        biasv[s][g] = (bih0[g*HH + u] + bhh0[g*HH + u]) * (g == 2 ? KLOG2E2 : KLOG2E);
      if (half == 0){
        #pragma unroll
        for (int kt = 0; kt < 2; ++kt)
          *(s8b*)(smem + ((w8*10 + s*2 + kt) << 10) + (l << 4)) =
              wfrag_s(Wih0 + (size_t)wrow*II + kt*32 + lq*8, wsc);
      }
      Wi2[s] = (lq < 2) ? wfrag_s(Wih0 + (size_t)wrow*II + 64 + lq*8, wsc) : zf;
      #pragma unroll
      for (int kt = 0; kt < 5; ++kt)
        Wh[s][kt] = wfrag_s(Whh0 + (size_t)wrow*HH + kt*32 + lq*8, wsc);
    }
    if (w8 == 7){                                       // pack x(0) -> xsh buf0
      const float* xp = x + (size_t)(b0 + lr) * TT * II + (l>>4)*20;
      short* xd = xsh + lr*XP + (l>>4)*20;
      #pragma unroll
      for (int i = 0; i < 5; ++i){
        float4 a = ld4(xp + i*4);
        s4b p; p[0]=f2bf(a.x); p[1]=f2bf(a.y); p[2]=f2bf(a.z); p[3]=f2bf(a.w);
        *(s4b*)(xd + i*4) = p;
      }
    }
    __syncthreads();                                    // weights + xsh[0]

    s8b h0a[5];
    #pragma unroll
    for (int kt = 0; kt < 5; ++kt) h0a[kt] = zf;
    float c0[NTILE] = {0.f,0.f,0.f,0.f,0.f};

    // accx(0) = bias + Wih0*x(0)
    s8b xa[3];
    {
      const short* xr = xsh + lr*XP;
      xa[0] = *(const s8b*)&xr[lq*8];
      xa[1] = *(const s8b*)&xr[32 + lq*8];
      xa[2] = (lq < 2) ? *(const s8b*)&xr[64 + lq*8] : zf;
    }
    f4 accx[NTILE];
    #pragma unroll
    for (int s = 0; s < NTILE; ++s){
      accx[s] = biasv[s];
      accx[s] = mfma16(*(const s8b*)(smem + ((w8*10 + s*2 + 0) << 10) + (l << 4)), xa[0], accx[s]);
      accx[s] = mfma16(*(const s8b*)(smem + ((w8*10 + s*2 + 1) << 10) + (l << 4)), xa[1], accx[s]);
      accx[s] = mfma16(Wi2[s], xa[2], accx[s]);
    }

    int credB = 0;
    for (int t = 0; t < TT; ++t){
      float4 xl0, xl1, xl2, xl3, xl4;                   // w8==7: x(t+1) early issue
      if (w8 == 7 && t+1 < TT){
        const float* xp = x + (size_t)(b0 + lr) * TT * II + (size_t)(t+1)*II + (l>>4)*20;
        xl0 = ld4(xp); xl1 = ld4(xp+4); xl2 = ld4(xp+8); xl3 = ld4(xp+12); xl4 = ld4(xp+16);
      }

      if (t >= DEPTH && credB < t - DEPTH + 1)
        poll_ge(prog, credB, t - DEPTH + 1, l);         // slot-reuse credit

      short* hb = hsh + (t&1)*16*HP;
      // ---- critical block: 25 pure-register MFMAs
      #pragma unroll
      for (int kt = 0; kt < 5; ++kt)
        #pragma unroll
        for (int s = 0; s < NTILE; ++s)
          accx[s] = mfma16(Wh[s][kt], h0a[kt], accx[s]);
      // ---- gates (exp2-folded)
      #pragma unroll
      for (int s = 0; s < NTILE; ++s){
        const float i_ = sig2(accx[s][0]);
        const float f_ = sig2(accx[s][1]);
        const float g_ = tanh2(accx[s][2]);
        const float o_ = sig2(accx[s][3]);
        const float cn = f_*c0[s] + i_*g_;
        c0[s] = cn;
        const float h = o_*(1.f - 2.f*rcpf(exp2f_(KLOG2E2*cn) + 1.f));
        hb[lr*HP + 4*(w8 + 8*s) + lq] = f2bf(h);
      }
      if (w8 == 7 && t+1 < TT){                         // pack x(t+1) -> xsh
        short* xd = xsh + ((t+1)&1)*16*XP + lr*XP + (l>>4)*20;
        float4 a[5] = {xl0, xl1, xl2, xl3, xl4};
        #pragma unroll
        for (int i = 0; i < 5; ++i){
          s4b p; p[0]=f2bf(a[i].x); p[1]=f2bf(a[i].y); p[2]=f2bf(a[i].z); p[3]=f2bf(a[i].w);
          *(s4b*)(xd + i*4) = p;
        }
      }
      __syncthreads();                                  // h0(t) + x(t+1) visible
      #pragma unroll
      for (int kt = 0; kt < 5; ++kt)
        h0a[kt] = *(const s8b*)&hb[lr*HP + kt*32 + lq*8];
      if (w8 < 5){                                      // ship frag kt=w8, tag t+1
        const s8b hf = h0a[w8];
        const unsigned long long tg = (unsigned long long)(t+1);
        unsigned long long u0 = (unsigned long long)(unsigned short)hf[0]
                              | ((unsigned long long)(unsigned short)hf[1] << 16)
                              | ((unsigned long long)(unsigned short)hf[2] << 32)
                              | (tg << 48);
        unsigned long long u1 = (unsigned long long)(unsigned short)hf[3]
                              | ((unsigned long long)(unsigned short)hf[4] << 16)
                              | ((unsigned long long)(unsigned short)hf[5] << 32)
                              | (tg << 48);
        unsigned long long u2 = (unsigned long long)(unsigned short)hf[6]
                              | ((unsigned long long)(unsigned short)hf[7] << 16)
                              | (tg << 32) | (tg << 48);
        unsigned long long* sl = ring + (size_t)(t & (DEPTH-1))*SLOT_U64;
        st64(sl + li, u0); st64(sl + 320 + li, u1); st64(sl + 640 + li, u2);
      }
      // ---- precompute accx(t+1) = bias + Wih0*x(t+1)
      {
        const short* xr = xsh + ((t+1)&1)*16*XP + lr*XP;
        xa[0] = *(const s8b*)&xr[lq*8];
        xa[1] = *(const s8b*)&xr[32 + lq*8];
        xa[2] = (lq < 2) ? *(const s8b*)&xr[64 + lq*8] : zf;
      }
      #pragma unroll
      for (int s = 0; s < NTILE; ++s){
        accx[s] = biasv[s];
        accx[s] = mfma16(*(const s8b*)(smem + ((w8*10 + s*2 + 0) << 10) + (l << 4)), xa[0], accx[s]);
        accx[s] = mfma16(*(const s8b*)(smem + ((w8*10 + s*2 + 1) << 10) + (l << 4)), xa[1], accx[s]);
        accx[s] = mfma16(Wi2[s], xa[2], accx[s]);
      }
    }
  }
  else {
    // ================= stage B: layer 1 + head (two halves) =================
    short* h0l   = (short*)(smem + 81920  + half*10752);   // [2][16*HP]
    short* hsh   = (short*)(smem + 103424 + half*10752);   // [2][16*HP]
    float* ypart = (float*)(smem + 124928 + half*1024);    // [2][8][16]
    f4* bias4    = (f4*)(smem + 126976);                   // [160] shared
    for (int i = tid; i < HH; i += NTHR){
      f4 b;
      #pragma unroll
      for (int g = 0; g < 4; ++g)
        b[g] = (bih1[g*HH + i] + bhh1[g*HH + i]) * (g == 2 ? KLOG2E2 : KLOG2E);
      bias4[i] = b;
    }
    // Whh1 ALL 25 frags in regs (on-path); Wih1 kt0..2 regs, kt3,4 LDS (shared).
    s8b Wi[NTILE][3], Wh[NTILE][5];
    float woutv[NTILE];
    #pragma unroll
    for (int s = 0; s < NTILE; ++s){
      const int ct = w8 + 8*s;
      const int wrow = q*HH + 4*ct + h2;
      woutv[s] = Wout[4*ct + lq];
      #pragma unroll
      for (int kt = 0; kt < 5; ++kt)
        Wh[s][kt] = wfrag_s(Whh1 + (size_t)wrow*HH + kt*32 + lq*8, wsc);
      #pragma unroll
      for (int kt = 0; kt < 3; ++kt)
        Wi[s][kt] = wfrag_s(Wih1 + (size_t)wrow*HH + kt*32 + lq*8, wsc);
      if (half == 0){
        #pragma unroll
        for (int kt = 3; kt < 5; ++kt)
          *(s8b*)(smem + ((w8*10 + s*2 + (kt-3)) << 10) + (l << 4)) =
              wfrag_s(Wih1 + (size_t)wrow*HH + kt*32 + lq*8, wsc);
      }
    }
    const float bo = bout[0];
    s8b h1a[5];
    #pragma unroll
    for (int kt = 0; kt < 5; ++kt) h1a[kt] = zf;
    float c1[NTILE] = {0.f,0.f,0.f,0.f,0.f};

    // prologue: spin-consume slot 0 (tag 1) -> h0l[0]; speculative loads slot 1
    unsigned long long in0 = 0, in1 = 0, in2 = 0;
    if (w8 < 5){
      const unsigned long long* src = ring;
      in0 = ld64(src + li); in1 = ld64(src + 320 + li); in2 = ld64(src + 640 + li);
      bool ok = ((int)(in0>>48)==1) && ((int)(in1>>48)==1) && ((int)(in2>>48)==1);
      while (__ballot(ok) != ~0ull){
        __builtin_amdgcn_s_sleep(1);
        in0 = ld64(src + li); in1 = ld64(src + 320 + li); in2 = ld64(src + 640 + li);
        ok = ((int)(in0>>48)==1) && ((int)(in1>>48)==1) && ((int)(in2>>48)==1);
      }
      s8b v;
      v[0]=(short)in0; v[1]=(short)(in0>>16); v[2]=(short)(in0>>32);
      v[3]=(short)in1; v[4]=(short)(in1>>16); v[5]=(short)(in1>>32);
      v[6]=(short)in2; v[7]=(short)(in2>>16);
      *(s8b*)&h0l[lr*HP + w8*32 + lq*8] = v;
      const unsigned long long* p1 = ring + SLOT_U64;
      in0 = ld64(p1 + li); in1 = ld64(p1 + 320 + li); in2 = ld64(p1 + 640 + li);
    }
    __syncthreads();

    // accx(0) = bias + Wih1*h0(0)
    f4 accx[NTILE];
    {
      const short* hp = h0l;
      #pragma unroll
      for (int s = 0; s < NTILE; ++s)
        accx[s] = bias4[4*(w8 + 8*s) + lq];
      #pragma unroll
      for (int kt = 0; kt < 3; ++kt){
        const s8b hf = *(const s8b*)&hp[lr*HP + kt*32 + lq*8];
        #pragma unroll
        for (int s = 0; s < NTILE; ++s) accx[s] = mfma16(Wi[s][kt], hf, accx[s]);
      }
      #pragma unroll
      for (int kt = 3; kt < 5; ++kt){
        const s8b hf = *(const s8b*)&hp[lr*HP + kt*32 + lq*8];
        #pragma unroll
        for (int s = 0; s < NTILE; ++s)
          accx[s] = mfma16(*(const s8b*)(smem + ((w8*10 + s*2 + (kt-3)) << 10) + (l << 4)), hf, accx[s]);
      }
    }

    for (int t = 0; t < TT; ++t){
      short* hb = hsh + (t&1)*16*HP;
      // ---- critical block: 25 pure-register MFMAs
      #pragma unroll
      for (int kt = 0; kt < 5; ++kt)
        #pragma unroll
        for (int s = 0; s < NTILE; ++s)
          accx[s] = mfma16(Wh[s][kt], h1a[kt], accx[s]);

      // validate slot t+1 (tag t+2; loads issued last step) -> h0l[(t+1)&1]
      if (w8 < 5 && t+1 < TT){
        const int tg = t+2;
        const unsigned long long* src = ring + (size_t)((t+1) & (DEPTH-1))*SLOT_U64;
        bool ok = ((int)(in0>>48)==tg) && ((int)(in1>>48)==tg) && ((int)(in2>>48)==tg);
        while (__ballot(ok) != ~0ull){
          __builtin_amdgcn_s_sleep(1);
          in0 = ld64(src + li); in1 = ld64(src + 320 + li); in2 = ld64(src + 640 + li);
          ok = ((int)(in0>>48)==tg) && ((int)(in1>>48)==tg) && ((int)(in2>>48)==tg);
        }
        s8b v;
        v[0]=(short)in0; v[1]=(short)(in0>>16); v[2]=(short)(in0>>32);
        v[3]=(short)in1; v[4]=(short)(in1>>16); v[5]=(short)(in1>>32);
        v[6]=(short)in2; v[7]=(short)(in2>>16);
        *(s8b*)&h0l[((t+1)&1)*16*HP + lr*HP + w8*32 + lq*8] = v;
      }

      // ---- gates + head partials (exp2-folded)
      float ysum = 0.f;
      #pragma unroll
      for (int s = 0; s < NTILE; ++s){
        const float i_ = sig2(accx[s][0]);
        const float f_ = sig2(accx[s][1]);
        const float g_ = tanh2(accx[s][2]);
        const float o_ = sig2(accx[s][3]);
        const float cn = f_*c1[s] + i_*g_;
        c1[s] = cn;
        const float h = o_*(1.f - 2.f*rcpf(exp2f_(KLOG2E2*cn) + 1.f));
        hb[lr*HP + 4*(w8 + 8*s) + lq] = f2bf(h);
        ysum += h * woutv[s];
      }
      ysum += __shfl_xor(ysum, 16, 64);
      ysum += __shfl_xor(ysum, 32, 64);
      if (l < 16) ypart[(t&1)*128 + w8*16 + l] = ysum;

      __syncthreads();                                 // h1(t), ypart, h0(t+1) visible
      #pragma unroll
      for (int kt = 0; kt < 5; ++kt)
        h1a[kt] = *(const s8b*)&hb[lr*HP + kt*32 + lq*8];
      if (w8 == 0 && l < 16){
        float s_ = bo;
        #pragma unroll
        for (int ww = 0; ww < NW; ++ww) s_ += ypart[(t&1)*128 + ww*16 + l];
        out[(size_t)(b0 + l)*TT + t] = fmaxf(s_, 0.f);
      }
      // ---- precompute accx(t+1) = bias + Wih1*h0(t+1)
      {
        const short* hp = h0l + ((t+1)&1)*16*HP;
        #pragma unroll
        for (int s = 0; s < NTILE; ++s)
          accx[s] = bias4[4*(w8 + 8*s) + lq];
        #pragma unroll
        for (int kt = 0; kt < 3; ++kt){
          const s8b hf = *(const s8b*)&hp[lr*HP + kt*32 + lq*8];
          #pragma unroll
          for (int s = 0; s < NTILE; ++s) accx[s] = mfma16(Wi[s][kt], hf, accx[s]);
        }
        #pragma unroll
        for (int kt = 3; kt < 5; ++kt){
          const s8b hf = *(const s8b*)&hp[lr*HP + kt*32 + lq*8];
          #pragma unroll
          for (int s = 0; s < NTILE; ++s)
            accx[s] = mfma16(*(const s8b*)(smem + ((w8*10 + s*2 + (kt-3)) << 10) + (l << 4)), hf, accx[s]);
        }
      }
      if (w8 < 5 && t+2 < TT){                         // speculative loads slot t+2
        const unsigned long long* p =
            ring + (size_t)((t+2) & (DEPTH-1))*SLOT_U64;
        in0 = ld64(p + li); in1 = ld64(p + 320 + li); in2 = ld64(p + 640 + li);
      }
      if (((t & 7) == 7) && w8 == 0 && l == 0)         // credit per half, post-barrier
        __hip_atomic_store(prog, t+1, __ATOMIC_RELEASE, __HIP_MEMORY_SCOPE_AGENT);
    }
  }
}

extern "C" void kernel_launch(void* const* d_in, const int* in_sizes, int n_in,
                              void* d_out, int out_size, void* d_ws, size_t ws_size,
                              hipStream_t stream)
{
  (void)in_sizes; (void)n_in; (void)out_size; (void)ws_size;
  (void)hipFuncSetAttribute(reinterpret_cast<const void*>(lstm2),
                            hipFuncAttributeMaxDynamicSharedMemorySize, SMEM_SZ);
  // zero credits + full h-ring (tag safety incl. across graph replays)
  (void)hipMemsetAsync(d_ws, 0, WS_ZERO, stream);
  lstm2<<<dim3(NGRP), dim3(NTHR), SMEM_SZ, stream>>>(   // 16 A + 16 B blocks
      (const float*)d_in[0],
      (const float*)d_in[1], (const float*)d_in[2],
      (const float*)d_in[3], (const float*)d_in[4],
      (const float*)d_in[5], (const float*)d_in[6],
      (const float*)d_in[7], (const float*)d_in[8],
      (const float*)d_in[9], (const float*)d_in[10],
      (float*)d_out, (char*)d_ws);
}

// Round 9
// 4655.231 us; speedup vs baseline: 3.8667x; 3.8667x over previous
//
#include <hip/hip_runtime.h>
#include <stdint.h>

// 2-layer LSTM (B=512,T=1024,I=80,H=160) on MI355X gfx950.
// Round-11: TRANS diet (combined-fraction gates). Evidence: R8's 4-wave/SIMD
// fusion spilled (VGPR 128->64 cap, 4x slower) -> TLP structurally capped at
// 2 waves/SIMD. Issue-budget model incl. quarter-rate TRANS pipe says gates'
// 100 TRANS instr/SIMD/step (~800cy) is the largest bucket. This round cuts
// TRANS 10->8 per unit with EXACT algebra (no approximation):
//   sig(i)tanh(g) = copysign(1-e_g, g)*rcp((1+e_i)(1+e_g)),
//        e_i=exp2(-i'), e_g=exp2(-|g'|)   (negative-exponent form: all
//        exp2 operands <=0 -> e in (0,1], no overflow, graceful saturation)
//   sig(o)tanh(c) analogous; sig(f) stays rcp(1+exp2(-f')).
// Base: verified R7 (exp2 weight-fold, builtins-only, software-RNE f2bf,
// tag=t+1 ring, full-ring memset, 64 blocks x 512 thr). R8 fusion REVERTED.

#define TT 1024
#define BATCH 512
#define II 80
#define HH 160

constexpr int BB    = 16;
constexpr int NGRP  = BATCH / BB;   // 32
constexpr int NW    = 8;
constexpr int NTHR  = NW * 64;      // 512
constexpr int NTILE = 5;            // 40 col-tiles / 8 waves
constexpr int DEPTH = 32;           // h-ring depth (power of 2)
constexpr int HP    = 168;          // LDS h row stride (shorts)
constexpr int XP    = 88;           // LDS x row stride (shorts)

typedef __attribute__((ext_vector_type(8))) short s8b;
typedef __attribute__((ext_vector_type(4))) short s4b;
typedef __attribute__((ext_vector_type(4))) float f4;

// ring: per slot, 3 words x 320 lanes (u64) = 960 u64 = 7680 B, word-major
constexpr int SLOT_U64 = 960;
constexpr size_t OFF_RING = 4096;
constexpr size_t RING_STRIDE = (size_t)DEPTH * SLOT_U64 * 8;   // 245760 B/group
constexpr size_t WS_ZERO = OFF_RING + (size_t)NGRP * RING_STRIDE; // 7868416

// dynamic LDS layout (bytes); size keeps 1 block/CU
constexpr int HSH_OFF = 81920;    // h dbuf [2][16*HP] shorts (10752)
constexpr int H0L_OFF = 92672;    // B: h0 dbuf [2][16*HP]; A: xsh dbuf [2][16*XP]
constexpr int YP_OFF  = 103424;   // B: ypart [2][8][16] float (1024)
constexpr int BS_OFF  = 104448;   // B: bias4 [160] f4 (2560)
constexpr int SMEM_SZ = 107648;

constexpr float KLOG2E  = 1.4426950408889634f;
constexpr float KLOG2E2 = 2.8853900817779268f;

__device__ __forceinline__ short f2bf(float x){
  uint32_t u = __builtin_bit_cast(uint32_t, x);
  u = (u + 0x7FFFu + ((u >> 16) & 1u)) >> 16;     // RNE (proven)
  return (short)u;
}
__device__ __forceinline__ float rcpf(float x){ return __builtin_amdgcn_rcpf(x); }
__device__ __forceinline__ float exp2f_(float x){ return __builtin_amdgcn_exp2f(x); }

__device__ __forceinline__ f4 mfma16(s8b a, s8b b, f4 c){
  return __builtin_amdgcn_mfma_f32_16x16x32_bf16(a, b, c, 0, 0, 0);
}

__device__ __forceinline__ float4 ld4(const float* p){ return *(const float4*)p; }
__device__ __forceinline__ s8b wfrag_s(const float* p, float sc){
  float4 a = ld4(p), b = ld4(p+4);
  s8b r;
  r[0]=f2bf(a.x*sc); r[1]=f2bf(a.y*sc); r[2]=f2bf(a.z*sc); r[3]=f2bf(a.w*sc);
  r[4]=f2bf(b.x*sc); r[5]=f2bf(b.y*sc); r[6]=f2bf(b.z*sc); r[7]=f2bf(b.w*sc);
  return r;
}

// Combined-fraction LSTM cell update. Preacts: i',f',o' scaled by log2(e),
// g' scaled by 2log2(e) (folded into weights/biases). Exact identities:
//   sig(f) = rcp(1 + exp2(-f'))
//   sig(i)tanh(g) = copysign(1 - e_g, g') * rcp((1+e_i)(1+e_g))
//   sig(o)tanh(c) = copysign(1 - e_c, cn) * rcp((1+e_o)(1+e_c))
// 8 TRANS (5 exp2 + 3 rcp) per unit, was 10. All exp2 args <= 0.
__device__ __forceinline__ float cell_upd(const f4 a, float& c){
  const float e_f = exp2f_(-a[1]);
  const float sf  = rcpf(1.f + e_f);
  const float e_i = exp2f_(-a[0]);
  const float e_g = exp2f_(-__builtin_fabsf(a[2]));
  const float r1  = rcpf((1.f + e_i) * (1.f + e_g));
  const float ig  = __builtin_copysignf(1.f - e_g, a[2]) * r1;
  const float cn  = sf * c + ig;
  c = cn;
  const float e_c = exp2f_(-__builtin_fabsf(KLOG2E2 * cn));
  const float e_o = exp2f_(-a[3]);
  const float r2  = rcpf((1.f + e_o) * (1.f + e_c));
  return __builtin_copysignf(1.f - e_c, cn) * r2;
}

__device__ __forceinline__ void st64(unsigned long long* p, unsigned long long v){
  __hip_atomic_store(p, v, __ATOMIC_RELAXED, __HIP_MEMORY_SCOPE_AGENT);
}
__device__ __forceinline__ unsigned long long ld64(const unsigned long long* p){
  return __hip_atomic_load(p, __ATOMIC_RELAXED, __HIP_MEMORY_SCOPE_AGENT);
}
__device__ __forceinline__ void poll_ge(int* p, int& shadow, int target, int lane){
  while (shadow < target){
    int v = 0;
    if (lane == 0) v = __hip_atomic_load(p, __ATOMIC_ACQUIRE, __HIP_MEMORY_SCOPE_AGENT);
    shadow = __shfl(v, 0, 64);
    if (shadow < target) __builtin_amdgcn_s_sleep(2);
  }
}

__global__ __launch_bounds__(NTHR, 1)   // block=512: 2 waves/SIMD -> 256-reg cap
void lstm2(const float* __restrict__ x,
           const float* __restrict__ Wih0, const float* __restrict__ Whh0,
           const float* __restrict__ bih0, const float* __restrict__ bhh0,
           const float* __restrict__ Wih1, const float* __restrict__ Whh1,
           const float* __restrict__ bih1, const float* __restrict__ bhh1,
           const float* __restrict__ Wout, const float* __restrict__ bout,
           float* __restrict__ out, char* __restrict__ ws)
{
  extern __shared__ char smem[];
  const int tid = threadIdx.x;
  const int w   = tid >> 6;
  const int l   = tid & 63;
  const int lq  = l >> 4;
  const int lr  = l & 15;
  const int q   = l & 3;          // weight-row gate index
  const int h2  = (l >> 2) & 3;   // weight-row unit-sub index
  const int stage = blockIdx.x >> 5;   // 0=A, 1=B
  const int gid   = blockIdx.x & 31;
  const int b0    = gid * BB;
  const int li    = w*64 + l;     // ring lane index (word-major layout)
  const float wsc = (q == 2) ? KLOG2E2 : KLOG2E;   // fold scale for this lane's rows

  int* prog = (int*)ws + gid;   // consumer progress (credit to A)
  unsigned long long* ring =
      (unsigned long long*)(ws + OFF_RING + (size_t)gid * RING_STRIDE);

  short* hsh = (short*)(smem + HSH_OFF);                // [2][16*HP]
  const s8b zf = {};

  if (stage == 0){
    // ================= stage A: layer 0 =================
    // Whh0 (25 frags) + Wih0 kt2 (5) in regs; Wih0 kt0,1 (10) in LDS. Scaled.
    short* xsh = (short*)(smem + H0L_OFF);              // [2][16*XP]
    s8b Wh[NTILE][5], Wi2[NTILE];
    f4 biasv[NTILE];
    #pragma unroll
    for (int s = 0; s < NTILE; ++s){
      const int ct = w + 8*s;
      const int wrow = q*HH + 4*ct + h2;
      const int u = 4*ct + lq;                          // per-lane unit
      #pragma unroll
      for (int g = 0; g < 4; ++g)
        biasv[s][g] = (bih0[g*HH + u] + bhh0[g*HH + u]) * (g == 2 ? KLOG2E2 : KLOG2E);
      #pragma unroll
      for (int kt = 0; kt < 2; ++kt)
        *(s8b*)(smem + ((w*10 + s*2 + kt) << 10) + (l << 4)) =
            wfrag_s(Wih0 + (size_t)wrow*II + kt*32 + lq*8, wsc);
      Wi2[s] = (lq < 2) ? wfrag_s(Wih0 + (size_t)wrow*II + 64 + lq*8, wsc) : zf;
      #pragma unroll
      for (int kt = 0; kt < 5; ++kt)
        Wh[s][kt] = wfrag_s(Whh0 + (size_t)wrow*HH + kt*32 + lq*8, wsc);
    }
    if (w == 7){                                        // pack x(0) -> xsh buf0
      const float* xp = x + (size_t)(b0 + lr) * TT * II + (l>>4)*20;
      short* xd = xsh + lr*XP + (l>>4)*20;
      #pragma unroll
      for (int i = 0; i < 5; ++i){
        float4 a = ld4(xp + i*4);
        s4b p; p[0]=f2bf(a.x); p[1]=f2bf(a.y); p[2]=f2bf(a.z); p[3]=f2bf(a.w);
        *(s4b*)(xd + i*4) = p;
      }
    }
    __syncthreads();                                    // weights + xsh[0]

    s8b h0a[5];
    #pragma unroll
    for (int kt = 0; kt < 5; ++kt) h0a[kt] = zf;
    float c0[NTILE] = {0.f,0.f,0.f,0.f,0.f};

    // accx(0) = bias + Wih0*x(0)
    s8b xa[3];
    {
      const short* xr = xsh + lr*XP;
      xa[0] = *(const s8b*)&xr[lq*8];
      xa[1] = *(const s8b*)&xr[32 + lq*8];
      xa[2] = (lq < 2) ? *(const s8b*)&xr[64 + lq*8] : zf;
    }
    f4 accx[NTILE];
    #pragma unroll
    for (int s = 0; s < NTILE; ++s){
      accx[s] = biasv[s];
      accx[s] = mfma16(*(const s8b*)(smem + ((w*10 + s*2 + 0) << 10) + (l << 4)), xa[0], accx[s]);
      accx[s] = mfma16(*(const s8b*)(smem + ((w*10 + s*2 + 1) << 10) + (l << 4)), xa[1], accx[s]);
      accx[s] = mfma16(Wi2[s], xa[2], accx[s]);
    }

    int credB = 0;
    for (int t = 0; t < TT; ++t){
      float4 xl0, xl1, xl2, xl3, xl4;                   // w7: x(t+1) early issue
      if (w == 7 && t+1 < TT){
        const float* xp = x + (size_t)(b0 + lr) * TT * II + (size_t)(t+1)*II + (l>>4)*20;
        xl0 = ld4(xp); xl1 = ld4(xp+4); xl2 = ld4(xp+8); xl3 = ld4(xp+12); xl4 = ld4(xp+16);
      }

      if (t >= DEPTH && credB < t - DEPTH + 1)
        poll_ge(prog, credB, t - DEPTH + 1, l);         // slot-reuse credit

      short* hb = hsh + (t&1)*16*HP;
      // ---- critical block: 25 pure-register MFMAs (weights as A-operand)
      #pragma unroll
      for (int kt = 0; kt < 5; ++kt)
        #pragma unroll
        for (int s = 0; s < NTILE; ++s)
          accx[s] = mfma16(Wh[s][kt], h0a[kt], accx[s]);
      // ---- gates (combined-fraction, 8 TRANS/unit)
      #pragma unroll
      for (int s = 0; s < NTILE; ++s){
        const float h = cell_upd(accx[s], c0[s]);
        hb[lr*HP + 4*(w + 8*s) + lq] = f2bf(h);
      }
      if (w == 7 && t+1 < TT){                          // pack x(t+1) -> xsh
        short* xd = xsh + ((t+1)&1)*16*XP + lr*XP + (l>>4)*20;
        float4 a[5] = {xl0, xl1, xl2, xl3, xl4};
        #pragma unroll
        for (int i = 0; i < 5; ++i){
          s4b p; p[0]=f2bf(a[i].x); p[1]=f2bf(a[i].y); p[2]=f2bf(a[i].z); p[3]=f2bf(a[i].w);
          *(s4b*)(xd + i*4) = p;
        }
      }
      __syncthreads();                                  // h0(t) + x(t+1) visible
      #pragma unroll
      for (int kt = 0; kt < 5; ++kt)
        h0a[kt] = *(const s8b*)&hb[lr*HP + kt*32 + lq*8];
      if (w < 5){                                       // ship frag kt=w, tag t+1 (never 0)
        const s8b hf = h0a[w];
        const unsigned long long tg = (unsigned long long)(t+1);
        unsigned long long u0 = (unsigned long long)(unsigned short)hf[0]
                              | ((unsigned long long)(unsigned short)hf[1] << 16)
                              | ((unsigned long long)(unsigned short)hf[2] << 32)
                              | (tg << 48);
        unsigned long long u1 = (unsigned long long)(unsigned short)hf[3]
                              | ((unsigned long long)(unsigned short)hf[4] << 16)
                              | ((unsigned long long)(unsigned short)hf[5] << 32)
                              | (tg << 48);
        unsigned long long u2 = (unsigned long long)(unsigned short)hf[6]
                              | ((unsigned long long)(unsigned short)hf[7] << 16)
                              | (tg << 32) | (tg << 48);
        unsigned long long* sl = ring + (size_t)(t & (DEPTH-1))*SLOT_U64;
        st64(sl + li, u0); st64(sl + 320 + li, u1); st64(sl + 640 + li, u2);
      }
      // ---- precompute accx(t+1) = bias + Wih0*x(t+1)
      {
        const short* xr = xsh + ((t+1)&1)*16*XP + lr*XP;
        xa[0] = *(const s8b*)&xr[lq*8];
        xa[1] = *(const s8b*)&xr[32 + lq*8];
        xa[2] = (lq < 2) ? *(const s8b*)&xr[64 + lq*8] : zf;
      }
      #pragma unroll
      for (int s = 0; s < NTILE; ++s){
        accx[s] = biasv[s];
        accx[s] = mfma16(*(const s8b*)(smem + ((w*10 + s*2 + 0) << 10) + (l << 4)), xa[0], accx[s]);
        accx[s] = mfma16(*(const s8b*)(smem + ((w*10 + s*2 + 1) << 10) + (l << 4)), xa[1], accx[s]);
        accx[s] = mfma16(Wi2[s], xa[2], accx[s]);
      }
    }
  }
  else {
    // ================= stage B: layer 1 + head =================
    short* h0l = (short*)(smem + H0L_OFF);             // [2][16*HP]
    float* ypart = (float*)(smem + YP_OFF);            // [2][8][16]
    f4* bias4 = (f4*)(smem + BS_OFF);                  // [160] per-unit gate bias
    for (int i = tid; i < HH; i += NTHR){
      f4 b;
      #pragma unroll
      for (int g = 0; g < 4; ++g)
        b[g] = (bih1[g*HH + i] + bhh1[g*HH + i]) * (g == 2 ? KLOG2E2 : KLOG2E);
      bias4[i] = b;
    }
    // Whh1 ALL 25 frags in regs (on-path); Wih1 kt0..2 regs, kt3,4 LDS. Scaled.
    s8b Wi[NTILE][3], Wh[NTILE][5];
    float woutv[NTILE];
    #pragma unroll
    for (int s = 0; s < NTILE; ++s){
      const int ct = w + 8*s;
      const int wrow = q*HH + 4*ct + h2;
      woutv[s] = Wout[4*ct + lq];
      #pragma unroll
      for (int kt = 0; kt < 5; ++kt)
        Wh[s][kt] = wfrag_s(Whh1 + (size_t)wrow*HH + kt*32 + lq*8, wsc);
      #pragma unroll
      for (int kt = 0; kt < 3; ++kt)
        Wi[s][kt] = wfrag_s(Wih1 + (size_t)wrow*HH + kt*32 + lq*8, wsc);
      #pragma unroll
      for (int kt = 3; kt < 5; ++kt)
        *(s8b*)(smem + ((w*10 + s*2 + (kt-3)) << 10) + (l << 4)) =
            wfrag_s(Wih1 + (size_t)wrow*HH + kt*32 + lq*8, wsc);
    }
    const float bo = bout[0];
    s8b h1a[5];
    #pragma unroll
    for (int kt = 0; kt < 5; ++kt) h1a[kt] = zf;
    float c1[NTILE] = {0.f,0.f,0.f,0.f,0.f};

    // prologue: spin-consume slot 0 (tag 1) -> h0l[0]; speculative loads slot 1
    unsigned long long in0 = 0, in1 = 0, in2 = 0;
    if (w < 5){
      const unsigned long long* src = ring;
      in0 = ld64(src + li); in1 = ld64(src + 320 + li); in2 = ld64(src + 640 + li);
      bool ok = ((int)(in0>>48)==1) && ((int)(in1>>48)==1) && ((int)(in2>>48)==1);
      while (__ballot(ok) != ~0ull){
        __builtin_amdgcn_s_sleep(1);
        in0 = ld64(src + li); in1 = ld64(src + 320 + li); in2 = ld64(src + 640 + li);
        ok = ((int)(in0>>48)==1) && ((int)(in1>>48)==1) && ((int)(in2>>48)==1);
      }
      s8b v;
      v[0]=(short)in0; v[1]=(short)(in0>>16); v[2]=(short)(in0>>32);
      v[3]=(short)in1; v[4]=(short)(in1>>16); v[5]=(short)(in1>>32);
      v[6]=(short)in2; v[7]=(short)(in2>>16);
      *(s8b*)&h0l[lr*HP + w*32 + lq*8] = v;
      const unsigned long long* p1 = ring + SLOT_U64;
      in0 = ld64(p1 + li); in1 = ld64(p1 + 320 + li); in2 = ld64(p1 + 640 + li);
    }
    __syncthreads();

    // accx(0) = bias + Wih1*h0(0)
    f4 accx[NTILE];
    {
      const short* hp = h0l;
      #pragma unroll
      for (int s = 0; s < NTILE; ++s)
        accx[s] = bias4[4*(w + 8*s) + lq];
      #pragma unroll
      for (int kt = 0; kt < 3; ++kt){
        const s8b hf = *(const s8b*)&hp[lr*HP + kt*32 + lq*8];
        #pragma unroll
        for (int s = 0; s < NTILE; ++s) accx[s] = mfma16(Wi[s][kt], hf, accx[s]);
      }
      #pragma unroll
      for (int kt = 3; kt < 5; ++kt){
        const s8b hf = *(const s8b*)&hp[lr*HP + kt*32 + lq*8];
        #pragma unroll
        for (int s = 0; s < NTILE; ++s)
          accx[s] = mfma16(*(const s8b*)(smem + ((w*10 + s*2 + (kt-3)) << 10) + (l << 4)), hf, accx[s]);
      }
    }

    for (int t = 0; t < TT; ++t){
      short* hb = hsh + (t&1)*16*HP;
      // ---- critical block: 25 pure-register MFMAs
      #pragma unroll
      for (int kt = 0; kt < 5; ++kt)
        #pragma unroll
        for (int s = 0; s < NTILE; ++s)
          accx[s] = mfma16(Wh[s][kt], h1a[kt], accx[s]);

      // validate slot t+1 (tag t+2; loads issued last step) -> h0l[(t+1)&1]
      if (w < 5 && t+1 < TT){
        const int tg = t+2;
        const unsigned long long* src = ring + (size_t)((t+1) & (DEPTH-1))*SLOT_U64;
        bool ok = ((int)(in0>>48)==tg) && ((int)(in1>>48)==tg) && ((int)(in2>>48)==tg);
        while (__ballot(ok) != ~0ull){
          __builtin_amdgcn_s_sleep(1);
          in0 = ld64(src + li); in1 = ld64(src + 320 + li); in2 = ld64(src + 640 + li);
          ok = ((int)(in0>>48)==tg) && ((int)(in1>>48)==tg) && ((int)(in2>>48)==tg);
        }
        s8b v;
        v[0]=(short)in0; v[1]=(short)(in0>>16); v[2]=(short)(in0>>32);
        v[3]=(short)in1; v[4]=(short)(in1>>16); v[5]=(short)(in1>>32);
        v[6]=(short)in2; v[7]=(short)(in2>>16);
        *(s8b*)&h0l[((t+1)&1)*16*HP + lr*HP + w*32 + lq*8] = v;
      }

      // ---- gates + head partials (combined-fraction, 8 TRANS/unit)
      float ysum = 0.f;
      #pragma unroll
      for (int s = 0; s < NTILE; ++s){
        const float h = cell_upd(accx[s], c1[s]);
        hb[lr*HP + 4*(w + 8*s) + lq] = f2bf(h);
        ysum += h * woutv[s];
      }
      ysum += __shfl_xor(ysum, 16, 64);
      ysum += __shfl_xor(ysum, 32, 64);
      if (l < 16) ypart[(t&1)*128 + w*16 + l] = ysum;

      __syncthreads();                                 // h1(t), ypart, h0(t+1) visible
      #pragma unroll
      for (int kt = 0; kt < 5; ++kt)
        h1a[kt] = *(const s8b*)&hb[lr*HP + kt*32 + lq*8];
      if (w == 0 && l < 16){
        float s_ = bo;
        #pragma unroll
        for (int ww = 0; ww < NW; ++ww) s_ += ypart[(t&1)*128 + ww*16 + l];
        out[(size_t)(b0 + l)*TT + t] = fmaxf(s_, 0.f);
      }
      // ---- precompute accx(t+1) = bias + Wih1*h0(t+1)
      {
        const short* hp = h0l + ((t+1)&1)*16*HP;
        #pragma unroll
        for (int s = 0; s < NTILE; ++s)
          accx[s] = bias4[4*(w + 8*s) + lq];
        #pragma unroll
        for (int kt = 0; kt < 3; ++kt){
          const s8b hf = *(const s8b*)&hp[lr*HP + kt*32 + lq*8];
          #pragma unroll
          for (int s = 0; s < NTILE; ++s) accx[s] = mfma16(Wi[s][kt], hf, accx[s]);
        }
        #pragma unroll
        for (int kt = 3; kt < 5; ++kt){
          const s8b hf = *(const s8b*)&hp[lr*HP + kt*32 + lq*8];
          #pragma unroll
          for (int s = 0; s < NTILE; ++s)
            accx[s] = mfma16(*(const s8b*)(smem + ((w*10 + s*2 + (kt-3)) << 10) + (l << 4)), hf, accx[s]);
        }
      }
      if (w < 5 && t+2 < TT){                          // speculative loads slot t+2
        const unsigned long long* p =
            ring + (size_t)((t+2) & (DEPTH-1))*SLOT_U64;
        in0 = ld64(p + li); in1 = ld64(p + 320 + li); in2 = ld64(p + 640 + li);
      }
      if (((t & 7) == 7) && tid == 0)                  // credit, post-barrier = free
        __hip_atomic_store(prog, t+1, __ATOMIC_RELEASE, __HIP_MEMORY_SCOPE_AGENT);
    }
  }
}

extern "C" void kernel_launch(void* const* d_in, const int* in_sizes, int n_in,
                              void* d_out, int out_size, void* d_ws, size_t ws_size,
                              hipStream_t stream)
{
  (void)in_sizes; (void)n_in; (void)out_size; (void)ws_size;
  (void)hipFuncSetAttribute(reinterpret_cast<const void*>(lstm2),
                            hipFuncAttributeMaxDynamicSharedMemorySize, SMEM_SZ);
  // zero credits + full h-ring (tag safety incl. across graph replays)
  (void)hipMemsetAsync(d_ws, 0, WS_ZERO, stream);
  lstm2<<<dim3(NGRP*2), dim3(NTHR), SMEM_SZ, stream>>>(
      (const float*)d_in[0],
      (const float*)d_in[1], (const float*)d_in[2],
      (const float*)d_in[3], (const float*)d_in[4],
      (const float*)d_in[5], (const float*)d_in[6],
      (const float*)d_in[7], (const float*)d_in[8],
      (const float*)d_in[9], (const float*)d_in[10],
      (float*)d_out, (char*)d_ws);
}